// Round 3
// baseline (185.194 us; speedup 1.0000x reference)
//
#include <hip/hip_runtime.h>

// Problem: B=64, H=W=512 fp32. out = x + (f - conv3x3(x,k_b)) / 6, zero pad,
// cross-correlation (no kernel flip).
#define BB 64
#define HH 512
#define WW 512
#define P  4   // output rows per wave strip

// One wave (64 lanes) covers a full 512-wide row: lane l owns floats
// [8l, 8l+8). It marches P consecutive rows with a sliding 3-row register
// window. Halos come from neighbor lanes via __shfl (image edge at lane 0/63
// is a true zero), so there are NO per-lane scalar/masked loads at all.
// 64 img * 128 strips = 8192 waves = 32/CU theoretical residency.

struct Row { float e[10]; };  // [left halo, 8 owned floats, right halo]

__device__ __forceinline__ Row load_row(const float* __restrict__ xrow,
                                        int c0, int lane) {
    Row r;
    const float4 q0 = *(const float4*)(xrow + c0);
    const float4 q1 = *(const float4*)(xrow + c0 + 4);
    r.e[1] = q0.x; r.e[2] = q0.y; r.e[3] = q0.z; r.e[4] = q0.w;
    r.e[5] = q1.x; r.e[6] = q1.y; r.e[7] = q1.z; r.e[8] = q1.w;
    // left halo = previous lane's last float; lane 0 = image edge -> 0
    const float lh = __shfl_up(q1.w, 1);
    const float rh = __shfl_down(q0.x, 1);
    r.e[0] = (lane == 0)  ? 0.f : lh;
    r.e[9] = (lane == 63) ? 0.f : rh;
    return r;
}

__device__ __forceinline__ Row zero_row() {
    Row r;
#pragma unroll
    for (int j = 0; j < 10; ++j) r.e[j] = 0.f;
    return r;
}

__global__ __launch_bounds__(256) void jacobi_march4_kernel(
    const float* __restrict__ x,
    const float* __restrict__ f,
    const float* __restrict__ k,
    float* __restrict__ out)
{
    const int lane = threadIdx.x & 63;
    const int wv   = threadIdx.x >> 6;

    // strip id is wave-uniform; readfirstlane makes it provably scalar so
    // kernel weights become s_load and row bases stay in SGPRs.
    int S = blockIdx.x * 4 + wv;
    S = __builtin_amdgcn_readfirstlane(S);
    const int g  = S & 127;      // row-group within image (128 groups of P=4)
    const int b  = S >> 7;       // batch index
    const int r0 = g * P;
    const int c0 = lane << 3;    // first owned column

    const size_t img = (size_t)b * HH * WW;
    const float* xb = x + img;
    const float* fb = f + img;
    float*       ob = out + img;

    const float* kb = k + b * 9; // scalar b -> s_load weights
    const float k00 = kb[0], k01 = kb[1], k02 = kb[2];
    const float k10 = kb[3], k11 = kb[4], k12 = kb[5];
    const float k20 = kb[6], k21 = kb[7], k22 = kb[8];

    Row m, c, p;
    m = (r0 > 0) ? load_row(xb + (size_t)(r0 - 1) * WW, c0, lane)
                 : zero_row();
    c = load_row(xb + (size_t)r0 * WW, c0, lane);

    const float inv6 = 1.f / 6.f;

#pragma unroll
    for (int ii = 0; ii < P; ++ii) {
        const int i = r0 + ii;
        // wave-uniform branch: zero row below the image
        p = (i + 1 < HH) ? load_row(xb + (size_t)(i + 1) * WW, c0, lane)
                         : zero_row();

        const float* frow = fb + (size_t)i * WW + c0;
        const float4 f0 = *(const float4*)(frow);
        const float4 f1 = *(const float4*)(frow + 4);

        float o[8];
#pragma unroll
        for (int j = 0; j < 8; ++j) {
            // cross-correlation: k[r][cc] * x[i+r-1][col+cc-1]
            float acc = k00 * m.e[j] + k01 * m.e[j + 1] + k02 * m.e[j + 2]
                      + k10 * c.e[j] + k11 * c.e[j + 1] + k12 * c.e[j + 2]
                      + k20 * p.e[j] + k21 * p.e[j + 1] + k22 * p.e[j + 2];
            const float fv = (j < 4) ? ((const float*)&f0)[j]
                                     : ((const float*)&f1)[j - 4];
            o[j] = c.e[j + 1] + (fv - acc) * inv6;
        }

        float* orow = ob + (size_t)i * WW + c0;
        *(float4*)(orow)     = make_float4(o[0], o[1], o[2], o[3]);
        *(float4*)(orow + 4) = make_float4(o[4], o[5], o[6], o[7]);

        m = c;
        c = p;
    }
}

extern "C" void kernel_launch(void* const* d_in, const int* in_sizes, int n_in,
                              void* d_out, int out_size, void* d_ws, size_t ws_size,
                              hipStream_t stream) {
    const float* x = (const float*)d_in[0];
    const float* f = (const float*)d_in[1];
    const float* k = (const float*)d_in[2];
    float* out = (float*)d_out;

    // 64 images * 128 strips = 8192 wave-strips; 4 waves per 256-block.
    const int blocks = (BB * (HH / P)) / 4;  // 2048
    jacobi_march4_kernel<<<blocks, 256, 0, stream>>>(x, f, k, out);
}

// Round 4
// 166.467 us; speedup vs baseline: 1.1125x; 1.1125x over previous
//
#include <hip/hip_runtime.h>

// Problem: B=64, H=W=512 fp32. out = x + (f - conv3x3(x,k_b)) / 6, zero pad,
// cross-correlation (no kernel flip).
//
// R4: R1's mapping (one aligned float4 of output per thread, contiguous
// full-line stores) with the VMEM instruction fat removed:
//  - b is derived from blockIdx.x only -> provably scalar -> the 9 kernel
//    weights compile to s_load (were 9 per-lane VMEM loads in R1).
//  - row halos come from neighbor lanes via __shfl (i is wave-uniform and a
//    wave covers 256 contiguous floats); only lane 0/63 do a single-active-
//    lane fallback load. R1's 6 full-wave strided scalar gathers -> 6 tiny
//    masked loads per wave.
// Per 64 output quads: 3 quad loads + 6 single-lane + 1 f + 1 store = 11
// wave-VMEM issues (R1: 20).
#define BB 64
#define HH 512
#define WW 512
#define W4 (WW / 4)

struct RowE { float4 v; float l, r; };  // quad + left/right halo floats

__device__ __forceinline__ RowE load_row(const float* __restrict__ xrow,
                                         int j0, int lane) {
    RowE r;
    r.v = *(const float4*)(xrow + j0);
    // neighbor-lane halos (all lanes participate in the shuffles)
    float lh = __shfl_up(r.v.w, 1);
    float rh = __shfl_down(r.v.x, 1);
    // wave-edge lanes: neighbor quad lives in another wave -> masked load
    if (lane == 0)  lh = (j0 > 0)      ? xrow[j0 - 1] : 0.f;
    if (lane == 63) rh = (j0 + 4 < WW) ? xrow[j0 + 4] : 0.f;
    r.l = lh; r.r = rh;
    return r;
}

__device__ __forceinline__ RowE zero_row() {
    RowE r;
    r.v = make_float4(0.f, 0.f, 0.f, 0.f);
    r.l = 0.f; r.r = 0.f;
    return r;
}

__global__ __launch_bounds__(256) void jacobi_v4_kernel(
    const float* __restrict__ x,
    const float* __restrict__ f,
    const float* __restrict__ k,
    float* __restrict__ out)
{
    const int tid  = threadIdx.x;
    const int lane = tid & 63;

    // 256 blocks per image -> b is scalar (SGPR) by construction.
    const int b = blockIdx.x >> 8;
    const int q = ((blockIdx.x & 255) << 8) + tid;  // quad index within image
    const int j4 = q & (W4 - 1);                    // wave-contiguous
    const int i  = q >> 7;                          // row, wave-uniform
    const int j0 = j4 << 2;

    const size_t img = (size_t)b * HH * WW;
    const float* xb = x + img;

    const float* kb = k + b * 9;  // scalar -> s_load
    const float k00 = kb[0], k01 = kb[1], k02 = kb[2];
    const float k10 = kb[3], k11 = kb[4], k12 = kb[5];
    const float k20 = kb[6], k21 = kb[7], k22 = kb[8];

    // three stencil rows (i-1, i, i+1); i is wave-uniform so the edge
    // branches are non-divergent.
    const RowE c = load_row(xb + (size_t)i * WW, j0, lane);
    const RowE m = (i > 0)      ? load_row(xb + (size_t)(i - 1) * WW, j0, lane)
                                : zero_row();
    const RowE p = (i < HH - 1) ? load_row(xb + (size_t)(i + 1) * WW, j0, lane)
                                : zero_row();

    // cross-correlation: k[r][cc] multiplies x[i+r-1][j+cc-1]
    float4 acc;
    acc.x = k00 * m.l   + k01 * m.v.x + k02 * m.v.y
          + k10 * c.l   + k11 * c.v.x + k12 * c.v.y
          + k20 * p.l   + k21 * p.v.x + k22 * p.v.y;
    acc.y = k00 * m.v.x + k01 * m.v.y + k02 * m.v.z
          + k10 * c.v.x + k11 * c.v.y + k12 * c.v.z
          + k20 * p.v.x + k21 * p.v.y + k22 * p.v.z;
    acc.z = k00 * m.v.y + k01 * m.v.z + k02 * m.v.w
          + k10 * c.v.y + k11 * c.v.z + k12 * c.v.w
          + k20 * p.v.y + k21 * p.v.z + k22 * p.v.w;
    acc.w = k00 * m.v.z + k01 * m.v.w + k02 * m.r
          + k10 * c.v.z + k11 * c.v.w + k12 * c.r
          + k20 * p.v.z + k21 * p.v.w + k22 * p.r;

    const size_t idx4 = (size_t)b * HH * W4 + (size_t)i * W4 + j4;
    const float4 fv = ((const float4*)f)[idx4];

    const float inv6 = 1.f / 6.f;
    float4 o;
    o.x = c.v.x + (fv.x - acc.x) * inv6;
    o.y = c.v.y + (fv.y - acc.y) * inv6;
    o.z = c.v.z + (fv.z - acc.z) * inv6;
    o.w = c.v.w + (fv.w - acc.w) * inv6;

    ((float4*)out)[idx4] = o;
}

extern "C" void kernel_launch(void* const* d_in, const int* in_sizes, int n_in,
                              void* d_out, int out_size, void* d_ws, size_t ws_size,
                              hipStream_t stream) {
    const float* x = (const float*)d_in[0];
    const float* f = (const float*)d_in[1];
    const float* kk = (const float*)d_in[2];
    float* out = (float*)d_out;

    const int blocks = (BB * HH * W4) / 256;  // 16384
    jacobi_v4_kernel<<<blocks, 256, 0, stream>>>(x, f, kk, out);
}